// Round 1
// baseline (560.051 us; speedup 1.0000x reference)
//
#include <hip/hip_runtime.h>
#include <math.h>

// FourierFilter: out = Re(IFFT(mask * FFT(x, axis=-1))), mask zeroes |freq| < 10 Hz
// x: [64, 128, 8192] f32.  8192 rows of length 8192.
//
// Strategy: pack two real rows into one complex sequence (mask is real+even, so
// filtering the packed signal filters both rows independently: Re -> row0, Im -> row1).
// Forward DIF FFT (natural -> bit-reversed), apply mask at bit-reversed positions,
// inverse DIT FFT (bit-reversed -> natural). No bit-reversal permutation needed.

#define FFT_N    8192
#define LOG2N    13
#define NTHREADS 256
#define NBUTTER  (FFT_N / 2)           // 4096 butterflies per stage
#define BPT      (NBUTTER / NTHREADS)  // 16 butterflies per thread per stage
#define TWN      (FFT_N / 4)           // 2048-entry twiddle table (half of N/2 via -i symmetry)

__device__ __forceinline__ float2 cmulf(float2 a, float2 b) {
    return make_float2(fmaf(a.x, b.x, -(a.y * b.y)),
                       fmaf(a.x, b.y,   a.y * b.x));
}

__global__ __launch_bounds__(NTHREADS, 2)
void fourier_filter_kernel(const float* __restrict__ x, float* __restrict__ out) {
    __shared__ float2 z[FFT_N];   // 64 KB
    __shared__ float2 tw[TWN];    // 16 KB: tw[j] = exp(-2*pi*i*j/N), j in [0, N/4)

    const int tid = threadIdx.x;
    const long long pair = blockIdx.x;
    const float* r0 = x + pair * (2LL * FFT_N);
    const float* r1 = r0 + FFT_N;

    // Build twiddle table (8 sincos per thread, once per block).
    for (int j = tid; j < TWN; j += NTHREADS) {
        float ang = -6.2831853071795864769f * (float)j / (float)FFT_N;
        float s, c;
        sincosf(ang, &s, &c);
        tw[j] = make_float2(c, s);
    }

    // Load two rows, packed: z[n] = x_row0[n] + i * x_row1[n]
    for (int i = 4 * tid; i < FFT_N; i += 4 * NTHREADS) {
        const float4 a = *reinterpret_cast<const float4*>(r0 + i);
        const float4 b = *reinterpret_cast<const float4*>(r1 + i);
        z[i + 0] = make_float2(a.x, b.x);
        z[i + 1] = make_float2(a.y, b.y);
        z[i + 2] = make_float2(a.z, b.z);
        z[i + 3] = make_float2(a.w, b.w);
    }
    __syncthreads();

    // ---- Forward FFT: Gentleman-Sande DIF, natural in -> bit-reversed out ----
    {
        int tsh = 0;  // twiddle stride shift: stride = (N/2)/len = 1<<tsh
        for (int len = FFT_N / 2; len >= 1; len >>= 1, ++tsh) {
            #pragma unroll
            for (int s = 0; s < BPT; ++s) {
                const int b  = tid + s * NTHREADS;
                const int j  = b & (len - 1);
                const int i0 = 2 * b - j;      // blk*2*len + j
                const int i1 = i0 + len;
                const float2 a = z[i0];
                const float2 c = z[i1];
                const float2 d = make_float2(a.x - c.x, a.y - c.y);
                const int ti = j << tsh;       // twiddle exponent, [0, N/2)
                float2 w = tw[ti & (TWN - 1)];
                if (ti & TWN) w = make_float2(w.y, -w.x);   // W^(j+2048) = -i * W^j
                z[i0] = make_float2(a.x + c.x, a.y + c.y);
                z[i1] = cmulf(d, w);
            }
            __syncthreads();
        }
    }

    // ---- Apply mask in bit-reversed domain: position p holds bin brev13(p) ----
    #pragma unroll
    for (int s = 0; s < FFT_N / NTHREADS; ++s) {
        const int p  = tid + s * NTHREADS;
        const int k  = (int)(__brev((unsigned)p) >> (32 - LOG2N));
        const int kf = min(k, FFT_N - k);      // |freq| index; k=0 -> 0
        if ((float)kf * (100.0f / 8192.0f) < 10.0f)   // |freqs[k]| < FREQ_CUTOFF
            z[p] = make_float2(0.0f, 0.0f);
    }
    __syncthreads();

    // ---- Inverse FFT: Cooley-Tukey DIT, bit-reversed in -> natural out ----
    {
        int tsh = LOG2N - 1;  // 12
        for (int len = 1; len <= FFT_N / 2; len <<= 1, --tsh) {
            #pragma unroll
            for (int s = 0; s < BPT; ++s) {
                const int b  = tid + s * NTHREADS;
                const int j  = b & (len - 1);
                const int i0 = 2 * b - j;
                const int i1 = i0 + len;
                const float2 a = z[i0];
                const float2 c = z[i1];
                const int ti = j << tsh;
                float2 w = tw[ti & (TWN - 1)];
                if (ti & TWN) w = make_float2(w.y, -w.x);
                w.y = -w.y;                    // conjugate for inverse
                const float2 t = cmulf(c, w);
                z[i0] = make_float2(a.x + t.x, a.y + t.y);
                z[i1] = make_float2(a.x - t.x, a.y - t.y);
            }
            __syncthreads();
        }
    }

    // ---- Store: Re -> row0, Im -> row1, scaled by 1/N ----
    const float invn = 1.0f / (float)FFT_N;
    float* o0 = out + pair * (2LL * FFT_N);
    float* o1 = o0 + FFT_N;
    for (int i = 4 * tid; i < FFT_N; i += 4 * NTHREADS) {
        const float2 a = z[i + 0];
        const float2 b = z[i + 1];
        const float2 c = z[i + 2];
        const float2 d = z[i + 3];
        *reinterpret_cast<float4*>(o0 + i) =
            make_float4(a.x * invn, b.x * invn, c.x * invn, d.x * invn);
        *reinterpret_cast<float4*>(o1 + i) =
            make_float4(a.y * invn, b.y * invn, c.y * invn, d.y * invn);
    }
}

extern "C" void kernel_launch(void* const* d_in, const int* in_sizes, int n_in,
                              void* d_out, int out_size, void* d_ws, size_t ws_size,
                              hipStream_t stream) {
    const float* x = (const float*)d_in[0];
    float* out = (float*)d_out;
    const int total  = in_sizes[0];              // 64*128*8192
    const int npairs = total / (2 * FFT_N);      // 4096 row pairs
    hipLaunchKernelGGL(fourier_filter_kernel, dim3(npairs), dim3(NTHREADS), 0, stream,
                       x, out);
}

// Round 2
// 257.605 us; speedup vs baseline: 2.1741x; 2.1741x over previous
//
#include <hip/hip_runtime.h>

// FourierFilter: out = Re(IFFT(mask * FFT(x, axis=-1))), mask zeroes |freq| < 10 Hz
// (kf <= 819 of 8192 @ 100 Hz sampling). x: [64,128,8192] f32.
//
// Two real rows packed into one complex row (mask real+even => filters separate).
// Forward: DIF, radices [2, 4,4,4,4,4,4] (natural -> digit-scrambled).
// Mask applied at scrambled positions via mixed-radix digit reversal.
// Inverse: DIT, mirrored radices (scrambled -> natural). No reorder pass.
// Fusions: global load + fwd radix-2 span 4096; {fwd len4, fwd len1, mask,
// inv len1, inv len4} in registers on 16-elem chunks; inv radix-2 + store.
// LDS: padded addressing phys(i)=i+(i>>4) kills power-of-2 bank conflicts.
// Twiddles via hardware __sinf/__cosf; W^2t,W^3t by complex squaring (no table).

#define FFT_N    8192
#define NTHREADS 256
#define PHY(i)   ((i) + ((i) >> 4))

__device__ __forceinline__ float2 cadd(float2 a, float2 b){ return make_float2(a.x+b.x, a.y+b.y); }
__device__ __forceinline__ float2 csub(float2 a, float2 b){ return make_float2(a.x-b.x, a.y-b.y); }
__device__ __forceinline__ float2 cmul(float2 a, float2 b){
    return make_float2(fmaf(a.x, b.x, -(a.y*b.y)), fmaf(a.x, b.y, a.y*b.x));
}
// W^t = exp(-2*pi*i*t/N)
__device__ __forceinline__ float2 twid(int t){
    float ang = (float)t * (-6.2831853071795864769f / (float)FFT_N);
    return make_float2(__cosf(ang), __sinf(ang));
}
__device__ __forceinline__ float2 twidc(int t){  // conj(W^t)
    float ang = (float)t * (-6.2831853071795864769f / (float)FFT_N);
    return make_float2(__cosf(ang), -__sinf(ang));
}
// multiply by W^(512*m) = exp(-i*m*pi/8), m in [0,9]; constants fold after unroll
__device__ __forceinline__ float2 cmul_w512(float2 v, int m, bool cj){
    const float C[10]  = {1.f, 0.92387953f, 0.70710678f, 0.38268343f, 0.f,
                          -0.38268343f, -0.70710678f, -0.92387953f, -1.f, -0.92387953f};
    const float Sg[10] = {0.f, -0.38268343f, -0.70710678f, -0.92387953f, -1.f,
                          -0.92387953f, -0.70710678f, -0.38268343f, 0.f, 0.38268343f};
    float si = cj ? -Sg[m] : Sg[m];
    return cmul(v, make_float2(C[m], si));
}

// Forward DIF radix-4 stage, butterfly span LEN (LDS-strided mapping).
template<int LEN>
__device__ __forceinline__ void fwd_r4(float2* zp, int tid){
    const int S = FFT_N / (4 * LEN);
    #pragma unroll
    for (int s = 0; s < 8; ++s){
        const int b  = tid + s * NTHREADS;
        const int j  = b & (LEN - 1);
        const int i0 = 4*b - 3*j;
        float2 A = zp[PHY(i0)];
        float2 B = zp[PHY(i0 + LEN)];
        float2 C = zp[PHY(i0 + 2*LEN)];
        float2 D = zp[PHY(i0 + 3*LEN)];
        float2 t0 = cadd(A,C), t1 = csub(A,C), t2 = cadd(B,D), t3 = csub(B,D);
        float2 y0 = cadd(t0,t2);
        float2 y2 = csub(t0,t2);
        float2 y1 = make_float2(t1.x + t3.y, t1.y - t3.x); // t1 - i*t3
        float2 y3 = make_float2(t1.x - t3.y, t1.y + t3.x); // t1 + i*t3
        float2 w1 = twid(j * S);
        float2 w2 = cmul(w1, w1);
        float2 w3 = cmul(w2, w1);
        zp[PHY(i0)]         = y0;
        zp[PHY(i0 +   LEN)] = cmul(y1, w1);
        zp[PHY(i0 + 2*LEN)] = cmul(y2, w2);
        zp[PHY(i0 + 3*LEN)] = cmul(y3, w3);
    }
}

// Inverse DIT radix-4 stage, span LEN.
template<int LEN>
__device__ __forceinline__ void inv_r4(float2* zp, int tid){
    const int S = FFT_N / (4 * LEN);
    #pragma unroll
    for (int s = 0; s < 8; ++s){
        const int b  = tid + s * NTHREADS;
        const int j  = b & (LEN - 1);
        const int i0 = 4*b - 3*j;
        float2 w1 = twidc(j * S);
        float2 w2 = cmul(w1, w1);
        float2 w3 = cmul(w2, w1);
        float2 A = zp[PHY(i0)];
        float2 B = cmul(zp[PHY(i0 +   LEN)], w1);
        float2 C = cmul(zp[PHY(i0 + 2*LEN)], w2);
        float2 D = cmul(zp[PHY(i0 + 3*LEN)], w3);
        float2 t0 = cadd(A,C), t1 = csub(A,C), t2 = cadd(B,D), t3 = csub(B,D);
        zp[PHY(i0)]         = cadd(t0,t2);
        zp[PHY(i0 + 2*LEN)] = csub(t0,t2);
        zp[PHY(i0 +   LEN)] = make_float2(t1.x - t3.y, t1.y + t3.x); // t1 + i*t3
        zp[PHY(i0 + 3*LEN)] = make_float2(t1.x + t3.y, t1.y - t3.x); // t1 - i*t3
    }
}

__global__ __launch_bounds__(NTHREADS, 2)
void fourier_filter_kernel(const float* __restrict__ x, float* __restrict__ out) {
    __shared__ float2 zp[FFT_N + FFT_N/16];   // 8704 * 8B = 68 KB, padded every 16

    const int tid = threadIdx.x;
    const long long pair = blockIdx.x;
    const float* r0 = x + pair * (2LL * FFT_N);
    const float* r1 = r0 + FFT_N;

    // ---- Pass 1: global load + forward radix-2 (span 4096), packed rows ----
    #pragma unroll
    for (int s = 0; s < 4; ++s){
        const int i = 4 * (tid + s * NTHREADS);
        const float4 a0 = *reinterpret_cast<const float4*>(r0 + i);
        const float4 a1 = *reinterpret_cast<const float4*>(r0 + i + 4096);
        const float4 b0 = *reinterpret_cast<const float4*>(r1 + i);
        const float4 b1 = *reinterpret_cast<const float4*>(r1 + i + 4096);
        #pragma unroll
        for (int e = 0; e < 4; ++e){
            float2 u = make_float2(((const float*)&a0)[e], ((const float*)&b0)[e]);
            float2 v = make_float2(((const float*)&a1)[e], ((const float*)&b1)[e]);
            zp[PHY(i + e)]        = cadd(u, v);
            zp[PHY(i + e + 4096)] = cmul(csub(u, v), twid(i + e));
        }
    }
    __syncthreads();

    // ---- Forward radix-4 stages ----
    fwd_r4<1024>(zp, tid); __syncthreads();
    fwd_r4<256>(zp, tid);  __syncthreads();
    fwd_r4<64>(zp, tid);   __syncthreads();
    fwd_r4<16>(zp, tid);   __syncthreads();

    // ---- Fused middle: fwd len=4, fwd len=1, MASK, inv len=1, inv len=4 ----
    #pragma unroll
    for (int s = 0; s < 2; ++s){
        const int c = tid + s * NTHREADS;   // chunk of 16
        const int base = 16 * c;
        float2 r[16];
        #pragma unroll
        for (int e = 0; e < 16; ++e) r[e] = zp[PHY(base + e)];

        // forward len=4 butterflies (j = 0..3), twiddles W^(q*j*512)
        #pragma unroll
        for (int j = 0; j < 4; ++j){
            float2 A=r[j], B=r[j+4], C=r[j+8], D=r[j+12];
            float2 t0=cadd(A,C), t1=csub(A,C), t2=cadd(B,D), t3=csub(B,D);
            float2 y0=cadd(t0,t2), y2=csub(t0,t2);
            float2 y1=make_float2(t1.x+t3.y, t1.y-t3.x);
            float2 y3=make_float2(t1.x-t3.y, t1.y+t3.x);
            r[j]    = y0;
            r[j+4]  = cmul_w512(y1, j,   false);
            r[j+8]  = cmul_w512(y2, 2*j, false);
            r[j+12] = cmul_w512(y3, 3*j, false);
        }
        // forward len=1 DFT4 + mask + inverse len=1 DFT4 (unit twiddles)
        #pragma unroll
        for (int g = 0; g < 4; ++g){
            float2 A=r[4*g], B=r[4*g+1], C=r[4*g+2], D=r[4*g+3];
            float2 t0=cadd(A,C), t1=csub(A,C), t2=cadd(B,D), t3=csub(B,D);
            float2 yq[4];
            yq[0]=cadd(t0,t2); yq[2]=csub(t0,t2);
            yq[1]=make_float2(t1.x+t3.y, t1.y-t3.x);
            yq[3]=make_float2(t1.x-t3.y, t1.y+t3.x);
            #pragma unroll
            for (int q = 0; q < 4; ++q){
                const int p = base + 4*g + q;
                // bin index: mixed-radix digit reversal for radices [2,4,4,4,4,4,4]
                const int k = (p >> 12) | (((p >> 10) & 3) << 1) | (((p >> 8) & 3) << 3)
                            | (((p >> 6) & 3) << 5) | (((p >> 4) & 3) << 7)
                            | (((p >> 2) & 3) << 9) | ((p & 3) << 11);
                const int kf = min(k, FFT_N - k);
                if (kf <= 819) yq[q] = make_float2(0.f, 0.f);   // |freq| < 10 Hz
            }
            float2 u0=cadd(yq[0],yq[2]), u1=csub(yq[0],yq[2]);
            float2 u2=cadd(yq[1],yq[3]), u3=csub(yq[1],yq[3]);
            r[4*g]   = cadd(u0,u2);
            r[4*g+2] = csub(u0,u2);
            r[4*g+1] = make_float2(u1.x-u3.y, u1.y+u3.x);  // u1 + i*u3
            r[4*g+3] = make_float2(u1.x+u3.y, u1.y-u3.x);  // u1 - i*u3
        }
        // inverse len=4 butterflies
        #pragma unroll
        for (int j = 0; j < 4; ++j){
            float2 A = r[j];
            float2 B = cmul_w512(r[j+4],  j,   true);
            float2 C = cmul_w512(r[j+8],  2*j, true);
            float2 D = cmul_w512(r[j+12], 3*j, true);
            float2 t0=cadd(A,C), t1=csub(A,C), t2=cadd(B,D), t3=csub(B,D);
            r[j]    = cadd(t0,t2);
            r[j+8]  = csub(t0,t2);
            r[j+4]  = make_float2(t1.x-t3.y, t1.y+t3.x);
            r[j+12] = make_float2(t1.x+t3.y, t1.y-t3.x);
        }
        #pragma unroll
        for (int e = 0; e < 16; ++e) zp[PHY(base + e)] = r[e];
    }
    __syncthreads();

    // ---- Inverse radix-4 stages ----
    inv_r4<16>(zp, tid);   __syncthreads();
    inv_r4<64>(zp, tid);   __syncthreads();
    inv_r4<256>(zp, tid);  __syncthreads();
    inv_r4<1024>(zp, tid); __syncthreads();

    // ---- Final: inverse radix-2 (span 4096) + scale + store ----
    const float invn = 1.0f / (float)FFT_N;
    float* o0 = out + pair * (2LL * FFT_N);
    float* o1 = o0 + FFT_N;
    #pragma unroll
    for (int s = 0; s < 4; ++s){
        const int i = 4 * (tid + s * NTHREADS);
        float4 w0, w1v, w2v, w3v;
        #pragma unroll
        for (int e = 0; e < 4; ++e){
            float2 A = zp[PHY(i + e)];
            float2 B = cmul(zp[PHY(i + e + 4096)], twidc(i + e));
            float2 pp = cadd(A, B);
            float2 qq = csub(A, B);
            ((float*)&w0)[e]  = pp.x * invn;
            ((float*)&w1v)[e] = pp.y * invn;
            ((float*)&w2v)[e] = qq.x * invn;
            ((float*)&w3v)[e] = qq.y * invn;
        }
        *reinterpret_cast<float4*>(o0 + i)        = w0;
        *reinterpret_cast<float4*>(o1 + i)        = w1v;
        *reinterpret_cast<float4*>(o0 + i + 4096) = w2v;
        *reinterpret_cast<float4*>(o1 + i + 4096) = w3v;
    }
}

extern "C" void kernel_launch(void* const* d_in, const int* in_sizes, int n_in,
                              void* d_out, int out_size, void* d_ws, size_t ws_size,
                              hipStream_t stream) {
    const float* x = (const float*)d_in[0];
    float* out = (float*)d_out;
    const int total  = in_sizes[0];              // 64*128*8192
    const int npairs = total / (2 * FFT_N);      // 4096 row pairs
    hipLaunchKernelGGL(fourier_filter_kernel, dim3(npairs), dim3(NTHREADS), 0, stream,
                       x, out);
}

// Round 3
// 137.484 us; speedup vs baseline: 4.0736x; 1.8737x over previous
//
#include <hip/hip_runtime.h>

// FourierFilter: out = Re(IFFT(mask * FFT(x, axis=-1))), mask zeroes bins with
// |freq| < 10 Hz (kf <= 819 of 8192 @ 100 Hz). x: [64,128,8192] f32.
//
// Register-resident four-step FFT. Two real rows packed into one complex row.
// 256 threads x 32 float2 regs. Radix-2 DIF stage spans decomposed 5+5+3:
//   phase1 (regs): spans 4096..256 on {c + 256m}  = const-twiddle FFT32 + post
//                  twiddle W_8192^{c*brev5(m)} (deferral valid: factor is
//                  block-uniform at every stage).
//   phase2 (regs): spans 128..8 on {256*blk + off3 + 8m}, c' = 32*off3.
//   phase3 (regs): contiguous FFT8s: fwd + MASK(brev13) + inv fused, no LDS.
//   inverse mirrors (conj pre-twiddle, then DIT).
// Only 4 LDS round-trips / 4 barriers (each thread's phase read-set == write-set).
// LDS pad phys(n)=n+(n>>6): all transposes <=2-way except phase3 (4-way, minor).

#define FFT_N 8192
#define NT    256
#define PHY(i) ((i) + ((i) >> 6))

__device__ __forceinline__ float2 cadd(float2 a, float2 b){ return make_float2(a.x+b.x, a.y+b.y); }
__device__ __forceinline__ float2 csub(float2 a, float2 b){ return make_float2(a.x-b.x, a.y-b.y); }
__device__ __forceinline__ float2 cmul(float2 a, float2 b){
    return make_float2(fmaf(a.x, b.x, -(a.y*b.y)), fmaf(a.x, b.y, a.y*b.x));
}

// d * W_32^j (or conj), j in [0,16), compile-time after unroll -> branches fold.
__device__ __forceinline__ float2 mul_w32(float2 d, int j, bool cj){
  if (j == 0) return d;
  if (j == 8) return cj ? make_float2(-d.y, d.x) : make_float2(d.y, -d.x);
  const float C[16] = {1.f, 0.98078528f, 0.92387953f, 0.83146961f, 0.70710678f,
                       0.55557023f, 0.38268343f, 0.19509032f, 0.f, -0.19509032f,
                       -0.38268343f, -0.55557023f, -0.70710678f, -0.83146961f,
                       -0.92387953f, -0.98078528f};
  const float S[16] = {0.f, -0.19509032f, -0.38268343f, -0.55557023f, -0.70710678f,
                       -0.83146961f, -0.92387953f, -0.98078528f, -1.f, -0.98078528f,
                       -0.92387953f, -0.83146961f, -0.70710678f, -0.55557023f,
                       -0.38268343f, -0.19509032f};
  return cmul(d, make_float2(C[j], cj ? -S[j] : S[j]));
}

// DIF radix-2 stages, spans L..1 over SZ regs. Twiddle W_SZ^{j*(SZ/2/L)} == W_32^{j*16/L}.
template<int SZ, int L>
__device__ __forceinline__ void dif_rec(float2* r){
  #pragma unroll
  for (int g = 0; g < SZ; g += 2*L){
    #pragma unroll
    for (int j = 0; j < L; ++j){
      float2 u = r[g+j], v = r[g+j+L];
      r[g+j]   = cadd(u, v);
      r[g+j+L] = mul_w32(csub(u, v), j*(16/L), false);
    }
  }
  if constexpr (L > 1) dif_rec<SZ, L/2>(r);
}

// Inverse DIT radix-2 stages, spans 1..SZ/2 (conjugate twiddles), unnormalized.
template<int SZ, int L>
__device__ __forceinline__ void dit_rec(float2* r){
  #pragma unroll
  for (int g = 0; g < SZ; g += 2*L){
    #pragma unroll
    for (int j = 0; j < L; ++j){
      float2 a = r[g+j];
      float2 b = mul_w32(r[g+j+L], j*(16/L), true);
      r[g+j]   = cadd(a, b);
      r[g+j+L] = csub(a, b);
    }
  }
  if constexpr (2*L < SZ) dit_rec<SZ, 2*L>(r);
}

__host__ __device__ constexpr int brev5(int k){
  return ((k&1)<<4) | ((k&2)<<2) | (k&4) | ((k&8)>>2) | ((k&16)>>4);
}

// r[brev5(k)] *= W_8192^{cbase*k} (or conj), k=1..31, via 1 sincos + power chain.
__device__ __forceinline__ void twiddle_scale(float2* r, int cbase, bool cj){
  float s, c;
  __sincosf((float)cbase * -7.6699039394282061e-4f, &s, &c);  // -2*pi/8192
  if (cj) s = -s;
  const float2 w1 = make_float2(c, s);
  float2 w = w1;
  r[brev5(1)] = cmul(r[brev5(1)], w);
  #pragma unroll
  for (int k = 2; k < 32; ++k){
    w = cmul(w, w1);
    r[brev5(k)] = cmul(r[brev5(k)], w);
  }
}

__global__ __launch_bounds__(NT, 2)
void fourier_filter_kernel(const float* __restrict__ x, float* __restrict__ out){
  __shared__ float2 zs[FFT_N + FFT_N/64];   // 8320 * 8B = 65 KB (padded every 64)
  const int t = threadIdx.x;
  const long long pair = blockIdx.x;
  const float* r0 = x + pair * (2LL * FFT_N);
  const float* r1 = r0 + FFT_N;
  float2 r[32];

  // ---- fwd phase 1: spans 4096..256 on {t + 256m} (coalesced global load) ----
  #pragma unroll
  for (int m = 0; m < 32; ++m){
    const int n = t + (m << 8);
    r[m] = make_float2(__builtin_nontemporal_load(r0 + n),
                       __builtin_nontemporal_load(r1 + n));
  }
  dif_rec<32, 16>(r);
  twiddle_scale(r, t, false);
  #pragma unroll
  for (int m = 0; m < 32; ++m) zs[PHY(t + (m<<8))] = r[m];
  __syncthreads();

  // ---- fwd phase 2: spans 128..8 on {256*(t>>3) + (t&7) + 8m} ----
  const int base2 = ((t >> 3) << 8) | (t & 7);
  #pragma unroll
  for (int m = 0; m < 32; ++m) r[m] = zs[PHY(base2 + (m<<3))];
  dif_rec<32, 16>(r);
  twiddle_scale(r, (t & 7) << 5, false);
  #pragma unroll
  for (int m = 0; m < 32; ++m) zs[PHY(base2 + (m<<3))] = r[m];
  __syncthreads();

  // ---- phase 3: fwd spans 4,2,1 + MASK + inv spans 1,2,4 on {32t + e} ----
  #pragma unroll
  for (int e = 0; e < 32; ++e) r[e] = zs[PHY((t<<5) + e)];
  #pragma unroll
  for (int g = 0; g < 4; ++g) dif_rec<8, 4>(r + 8*g);
  #pragma unroll
  for (int e = 0; e < 32; ++e){
    const int p  = (t << 5) + e;
    const int k  = (int)(__brev((unsigned)p) >> 19);   // brev13: p holds bin k
    const int kf = min(k, FFT_N - k);
    if (kf <= 819) r[e] = make_float2(0.f, 0.f);       // |freq| < 10 Hz
  }
  #pragma unroll
  for (int g = 0; g < 4; ++g) dit_rec<8, 1>(r + 8*g);
  #pragma unroll
  for (int e = 0; e < 32; ++e) zs[PHY((t<<5) + e)] = r[e];
  __syncthreads();

  // ---- inv phase 2: conj pre-twiddle, then DIT spans 8..128 ----
  #pragma unroll
  for (int m = 0; m < 32; ++m) r[m] = zs[PHY(base2 + (m<<3))];
  twiddle_scale(r, (t & 7) << 5, true);
  dit_rec<32, 1>(r);
  #pragma unroll
  for (int m = 0; m < 32; ++m) zs[PHY(base2 + (m<<3))] = r[m];
  __syncthreads();

  // ---- inv phase 1: conj pre-twiddle, DIT spans 256..4096, store ----
  #pragma unroll
  for (int m = 0; m < 32; ++m) r[m] = zs[PHY(t + (m<<8))];
  twiddle_scale(r, t, true);
  dit_rec<32, 1>(r);
  const float invn = 1.f / (float)FFT_N;
  float* o0 = out + pair * (2LL * FFT_N);
  float* o1 = o0 + FFT_N;
  #pragma unroll
  for (int m = 0; m < 32; ++m){
    const int n = t + (m << 8);
    __builtin_nontemporal_store(r[m].x * invn, o0 + n);
    __builtin_nontemporal_store(r[m].y * invn, o1 + n);
  }
}

extern "C" void kernel_launch(void* const* d_in, const int* in_sizes, int n_in,
                              void* d_out, int out_size, void* d_ws, size_t ws_size,
                              hipStream_t stream) {
  const float* x = (const float*)d_in[0];
  float* out = (float*)d_out;
  const int total  = in_sizes[0];              // 64*128*8192
  const int npairs = total / (2 * FFT_N);      // 4096 row pairs
  hipLaunchKernelGGL(fourier_filter_kernel, dim3(npairs), dim3(NT), 0, stream,
                     x, out);
}